// Round 4
// baseline (138.535 us; speedup 1.0000x reference)
//
#include <hip/hip_runtime.h>
#include <math.h>

#define EPS 1e-6f
#define C_CH 64          // channels (fixed by reference)
#define BPS_A 256        // blocks per segment, reduction pass
#define BPS_C 256        // blocks per segment, apply pass

typedef float f32x4 __attribute__((ext_vector_type(4)));  // native vec for builtins

// ---------------------------------------------------------------------------
// Pass A: per-block partial sum-of-squares per channel. FORWARD sweep.
// grid = B * BPS_A, block = 256 threads. Unroll-2 over 16-row chunks.
// Writes partial[blockIdx.x][64] (deterministic, no atomics).
// Leaves the TAIL of feat resident in Infinity Cache for pass C.
// ---------------------------------------------------------------------------
__global__ __launch_bounds__(256) void sumsq_partial(
    const float4* __restrict__ feat,   // [N][16] float4 view of [N][64] f32
    const int* __restrict__ offset,    // [B] cumulative (exclusive end)
    float* __restrict__ partial)       // [B*BPS_A][64]
{
    const int seg  = blockIdx.x / BPS_A;
    const int bip  = blockIdx.x - seg * BPS_A;
    const int start = (seg == 0) ? 0 : offset[seg - 1];
    const int end   = offset[seg];

    const int t    = threadIdx.x;
    const int c4   = t & 15;    // float4 index within row
    const int rsub = t >> 4;    // row within 16-row chunk

    float4 a0 = make_float4(0.f, 0.f, 0.f, 0.f);
    float4 a1 = make_float4(0.f, 0.f, 0.f, 0.f);

    const int stride = BPS_A * 32;      // 2 chunks of 16 rows per iter
    for (int row = start + bip * 32 + rsub; row < end; row += stride) {
        float4 v = feat[row * 16 + c4];
        a0.x = fmaf(v.x, v.x, a0.x);
        a0.y = fmaf(v.y, v.y, a0.y);
        a0.z = fmaf(v.z, v.z, a0.z);
        a0.w = fmaf(v.w, v.w, a0.w);
        int row2 = row + 16;
        if (row2 < end) {
            float4 w = feat[row2 * 16 + c4];
            a1.x = fmaf(w.x, w.x, a1.x);
            a1.y = fmaf(w.y, w.y, a1.y);
            a1.z = fmaf(w.z, w.z, a1.z);
            a1.w = fmaf(w.w, w.w, a1.w);
        }
    }
    a0.x += a1.x; a0.y += a1.y; a0.z += a1.z; a0.w += a1.w;

    __shared__ float lds[16][C_CH];
    lds[rsub][4 * c4 + 0] = a0.x;
    lds[rsub][4 * c4 + 1] = a0.y;
    lds[rsub][4 * c4 + 2] = a0.z;
    lds[rsub][4 * c4 + 3] = a0.w;
    __syncthreads();

    if (t < C_CH) {
        float s = 0.f;
        #pragma unroll
        for (int r = 0; r < 16; ++r) s += lds[r][t];
        partial[blockIdx.x * C_CH + t] = s;
    }
}

// ---------------------------------------------------------------------------
// Pass C (fused finalize + apply), REVERSE sweep:
// The whole grid walks feat in DESCENDING address order so the tail of feat
// (most-recently cached by pass A's forward sweep) is read first — converts
// the LRU capacity pathology (feat == 256 MB == L3 size) into L3 hits.
// Prelude: every block redundantly reduces its segment's partials (L2-hot).
// Nontemporal stores keep `out` from evicting feat from Infinity Cache.
// ---------------------------------------------------------------------------
__global__ __launch_bounds__(256) void apply_kernel(
    const float4* __restrict__ feat,
    const int* __restrict__ offset,
    const float* __restrict__ partial,  // [B*BPS_A][64]
    const float* __restrict__ gamma,    // [64]
    const float4* __restrict__ beta4,   // [16] float4 view of beta[64]
    f32x4* __restrict__ out)
{
    // global reverse: first-dispatched block handles the highest addresses
    const int lin = gridDim.x - 1 - blockIdx.x;
    const int seg = lin / BPS_C;
    const int bip = lin - seg * BPS_C;
    const int start = (seg == 0) ? 0 : offset[seg - 1];
    const int end   = offset[seg];

    const int t    = threadIdx.x;
    const int c    = t & 63;     // channel
    const int q    = t >> 6;     // quarter (0..3)

    __shared__ float red[4][C_CH];
    __shared__ float mulsh[C_CH];

    // --- prelude: per-block finalize (partial buffer is tiny & L2-hot) ---
    {
        float s = 0.f;
        const float* p = partial + (seg * BPS_A) * C_CH + c;
        for (int b = q; b < BPS_A; b += 4) s += p[b * C_CH];
        red[q][c] = s;
        __syncthreads();
        if (t < C_CH) {
            float tot  = red[0][c] + red[1][c] + red[2][c] + red[3][c];
            float resp = sqrtf(tot);
            float m = resp;
            #pragma unroll
            for (int off = 1; off < 64; off <<= 1) m += __shfl_xor(m, off, 64);
            float mean = m * (1.0f / 64.0f);
            float rn   = resp / (mean + EPS);
            mulsh[c] = 1.0f + gamma[c] * rn;
        }
        __syncthreads();
    }

    const int c4   = t & 15;
    const int rsub = t >> 4;
    const float4 mm = ((const float4*)mulsh)[c4];
    const float4 bt = beta4[c4];

    const int stride = BPS_C * 32;          // rows per grid-chunk iteration
    const int base   = start + bip * 32;    // this block's chunk base
    // iterate chunk index k DESCENDING (highest addresses first)
    int k = (base < end) ? (end - 1 - base) / stride : -1;
    for (; k >= 0; --k) {
        const int r0 = base + k * stride;
        int row2 = r0 + 16 + rsub;          // upper half first (higher addr)
        if (row2 < end) {
            float4 w = feat[row2 * 16 + c4];
            f32x4 o2;
            o2.x = fmaf(w.x, mm.x, bt.x);
            o2.y = fmaf(w.y, mm.y, bt.y);
            o2.z = fmaf(w.z, mm.z, bt.z);
            o2.w = fmaf(w.w, mm.w, bt.w);
            __builtin_nontemporal_store(o2, &out[row2 * 16 + c4]);
        }
        int row = r0 + rsub;
        if (row < end) {
            float4 v = feat[row * 16 + c4];
            f32x4 o;
            o.x = fmaf(v.x, mm.x, bt.x);
            o.y = fmaf(v.y, mm.y, bt.y);
            o.z = fmaf(v.z, mm.z, bt.z);
            o.w = fmaf(v.w, mm.w, bt.w);
            __builtin_nontemporal_store(o, &out[row * 16 + c4]);
        }
    }
}

// ---------------------------------------------------------------------------
extern "C" void kernel_launch(void* const* d_in, const int* in_sizes, int n_in,
                              void* d_out, int out_size, void* d_ws, size_t ws_size,
                              hipStream_t stream)
{
    const float4* feat   = (const float4*)d_in[0];
    const int*    offset = (const int*)d_in[1];
    const float*  gamma  = (const float*)d_in[2];
    const float4* beta4  = (const float4*)d_in[3];
    f32x4*        out    = (f32x4*)d_out;

    const int B = in_sizes[1];   // number of segments (8)

    float* partial = (float*)d_ws;   // B*BPS_A*64 floats = 512 KB for B=8

    sumsq_partial<<<B * BPS_A, 256, 0, stream>>>(feat, offset, partial);
    apply_kernel<<<B * BPS_C, 256, 0, stream>>>(feat, offset, partial,
                                                gamma, beta4, out);
}